// Round 4
// baseline (105.601 us; speedup 1.0000x reference)
//
#include <hip/hip_runtime.h>
#include <math.h>

// B=8, H=W=512, N=50 pos + 50 neg clicks (from reference setup_inputs).
constexpr int B = 8, H = 512, W = 512, N = 50;
constexpr int TS = 32;                        // 32x32 pixel tile per block
constexpr int TPB = (H / TS) * (W / TS);      // 256 tiles per batch image
constexpr int NBLOCKS = B * TPB;              // 2048
constexpr float INF = 3.0e38f;

// Fused kernel:
//  1. Per-tile exact point pruning: keep point q iff dmin2(q,tile) <= B*,
//     B* = min_q dmax2(q,tile). Retains every pixel's argmin (ties incl.);
//     pruned points are STRICTLY farther than the pixel min, so they can't
//     even tie.
//  2. Combined pos/neg stream with parity tag: score = 2*d2 + tag
//     (pos tag=1) minus the even pixel-norm term (dropped: preserves order
//     AND parity). min over all points; parity 1 <=> min_pos2 < min_neg2
//     (strict, tie -> 0) — matches reference exactly. Scores are exact
//     integers in +-2^22; cast via SIGNED int (R2 bug: unsigned cast
//     clamped negative scores to 0).
//  3. BCE loss partial per block; last-finished block reduces partials in
//     fixed order (bit-deterministic).
__global__ __launch_bounds__(256) void psl_fused(
    const float* __restrict__ out,
    const int*   __restrict__ pos,
    const int*   __restrict__ neg,
    float*       __restrict__ dout,
    float*       __restrict__ partials,
    int*         __restrict__ counter)
{
    __shared__ float4 s_pts[2 * N + 4];   // pruned list (+ pad sentinels)
    __shared__ float  s_red[4];
    __shared__ int    s_cnt;
    __shared__ int    s_lastf;

    const int bid = blockIdx.x;          // 0..2047
    const int t   = threadIdx.x;
    const int b   = bid >> 8;            // 256 tiles per batch
    const int ty  = (bid >> 4) & 15;
    const int tx  = bid & 15;
    const float y0f = (float)(ty * TS);
    const float x0f = (float)(tx * TS);

    if (t == 0) s_cnt = 0;

    // ---- Pruning prologue (threads 0..99 hold one point each) ----
    float dmax2 = INF;
    float dmin2 = 0.0f, c0 = 0.0f, c1 = 0.0f, c2 = 0.0f;
    if (t < 2 * N) {
        const int* src = (t < N) ? pos : neg;
        const int  idx = (t < N) ? t : t - N;
        int2 p = ((const int2*)src)[b * N + idx];
        const float fy = (float)p.x, fx = (float)p.y;   // (ycoord, xcoord)
        const float tag = (t < N) ? 1.0f : 0.0f;
        const float yhi = y0f + (float)(TS - 1), xhi = x0f + (float)(TS - 1);
        // exact integer distances to tile rect
        float dy = fmaxf(fmaxf(y0f - fy, fy - yhi), 0.0f);
        float dx = fmaxf(fmaxf(x0f - fx, fx - xhi), 0.0f);
        dmin2 = dy * dy + dx * dx;
        float dyM = fmaxf(fy - y0f, yhi - fy);
        float dxM = fmaxf(fx - x0f, xhi - fx);
        dmax2 = dyM * dyM + dxM * dxM;
        c0 = -4.0f * fx;
        c1 = -4.0f * fy;
        c2 = 2.0f * (fx * fx + fy * fy) + tag;   // < 2^21, exact
    }
    // block-min of dmax2 -> bound
    float m = dmax2;
    #pragma unroll
    for (int off = 32; off > 0; off >>= 1)
        m = fminf(m, __shfl_down(m, off, 64));
    if ((t & 63) == 0) s_red[t >> 6] = m;
    __syncthreads();
    const float bound = fminf(fminf(s_red[0], s_red[1]),
                              fminf(s_red[2], s_red[3]));
    if (t < 2 * N && dmin2 <= bound) {
        int k = atomicAdd(&s_cnt, 1);   // order-free: min is commutative
        s_pts[k] = make_float4(c0, c1, c2, 0.0f);
    }
    __syncthreads();
    if (t == 0) {                        // pad to multiple of 4 with sentinels
        int k0 = s_cnt, kp = (k0 + 3) & ~3;
        for (int i = k0; i < kp; ++i)
            s_pts[i] = make_float4(0.0f, 0.0f, INF, 0.0f);
        s_cnt = kp;
    }
    __syncthreads();
    const int K = s_cnt;

    // ---- Pixel loop: 4 consecutive px per thread ----
    const int r   = t >> 3;              // row in tile 0..31
    const int cc  = (t & 7) << 2;        // col base 0..28
    const int y   = ty * TS + r;
    const int x   = tx * TS + cc;
    const float yf = (float)y;
    const float xf = (float)x;

    float mn[4] = {INF, INF, INF, INF};
    for (int n = 0; n < K; n += 4) {
        #pragma unroll
        for (int j = 0; j < 4; ++j) {
            float4 P = s_pts[n + j];
            float cy = fmaf(P.y, yf, P.z);          // exact
            mn[0] = fminf(mn[0], fmaf(P.x, xf,          cy));
            mn[1] = fminf(mn[1], fmaf(P.x, xf + 1.0f,   cy));
            mn[2] = fminf(mn[2], fmaf(P.x, xf + 2.0f,   cy));
            mn[3] = fminf(mn[3], fmaf(P.x, xf + 3.0f,   cy));
        }
    }

    const size_t pix = ((size_t)(b * H + y)) * W + x;
    float4 xv = *(const float4*)(out + pix);        // 16B-aligned
    const float xs[4] = {xv.x, xv.y, xv.z, xv.w};

    float lsum = 0.0f;
    #pragma unroll
    for (int j = 0; j < 4; ++j) {
        int mi = (int)mn[j];                        // exact int (can be <0)
        float z = (float)(mi & 1);                  // two's-complement parity
        dout[1 + pix + j] = z;
        float xx = xs[j];
        lsum += fmaxf(xx, 0.0f) - xx * z + __logf(1.0f + __expf(-fabsf(xx)));
    }

    // ---- block reduction of loss ----
    #pragma unroll
    for (int off = 32; off > 0; off >>= 1)
        lsum += __shfl_down(lsum, off, 64);
    __syncthreads();                     // s_red reuse safe
    if ((t & 63) == 0) s_red[t >> 6] = lsum;
    __syncthreads();

    if (t == 0) {
        float bsum = (s_red[0] + s_red[1]) + (s_red[2] + s_red[3]);
        __hip_atomic_store(&partials[bid], bsum, __ATOMIC_RELEASE,
                           __HIP_MEMORY_SCOPE_AGENT);
        int prev = __hip_atomic_fetch_add(counter, 1, __ATOMIC_ACQ_REL,
                                          __HIP_MEMORY_SCOPE_AGENT);
        s_lastf = (prev == NBLOCKS - 1);
    }
    __syncthreads();

    // ---- last block: fixed-order deterministic final reduction ----
    if (s_lastf) {
        float s = 0.0f;
        #pragma unroll
        for (int i = 0; i < NBLOCKS / 256; ++i)
            s += __hip_atomic_load(&partials[t + i * 256], __ATOMIC_ACQUIRE,
                                   __HIP_MEMORY_SCOPE_AGENT);
        #pragma unroll
        for (int off = 32; off > 0; off >>= 1)
            s += __shfl_down(s, off, 64);
        if ((t & 63) == 0) s_red[t >> 6] = s;
        __syncthreads();
        if (t == 0)
            dout[0] = ((s_red[0] + s_red[1]) + (s_red[2] + s_red[3])) *
                      (1.0f / (float)(B * H * W));
    }
}

extern "C" void kernel_launch(void* const* d_in, const int* in_sizes, int n_in,
                              void* d_out, int out_size, void* d_ws, size_t ws_size,
                              hipStream_t stream) {
    const float* out_logits = (const float*)d_in[0];
    const int*   pos        = (const int*)d_in[1];
    const int*   neg        = (const int*)d_in[2];
    float* dout     = (float*)d_out;
    int*   counter  = (int*)d_ws;                       // 4 bytes
    float* partials = (float*)((char*)d_ws + 256);      // 2048 floats

    hipMemsetAsync(counter, 0, sizeof(int), stream);    // graph-capture legal
    psl_fused<<<NBLOCKS, 256, 0, stream>>>(out_logits, pos, neg, dout,
                                           partials, counter);
}

// Round 5
// 12.768 us; speedup vs baseline: 8.2706x; 8.2706x over previous
//
#include <hip/hip_runtime.h>
#include <math.h>

// B=8, H=W=512, N=50 pos + 50 neg clicks (from reference setup_inputs).
constexpr int B = 8, H = 512, W = 512, N = 50;
constexpr int TS = 32;                        // 32x32 pixel tile per block
constexpr int TPB = (H / TS) * (W / TS);      // 256 tiles per batch image
constexpr int NBLOCKS = B * TPB;              // 2048
constexpr float INF = 3.0e38f;

// Kernel 1 (no atomics — R4's single-counter ACQ_REL tail serialized 2048
// cross-XCD RMWs ~= 100us; two-kernel stream ordering is free):
//  1. Per-tile exact point pruning: keep point q iff dmin2(q,tile) <= B*,
//     B* = min_q dmax2(q,tile). Retains every pixel's argmin (ties incl.).
//  2. Combined pos/neg stream, parity tag: score = 2*d2 + tag (pos tag=1),
//     pixel-norm term dropped (even -> preserves order AND parity).
//     min-reduce; parity of (signed) integer min gives the mask with the
//     reference's strict-< tie semantics. All scores exact integers in
//     +-2^22 -> fp32-exact, bit-exact mask.
//  3. Per-block BCE partial -> partials[bid] (plain store).
__global__ __launch_bounds__(256) void psl_main(
    const float* __restrict__ out,
    const int*   __restrict__ pos,
    const int*   __restrict__ neg,
    float*       __restrict__ dout,
    float*       __restrict__ partials)
{
    __shared__ float4 s_pts[2 * N + 4];   // pruned list (+ pad sentinels)
    __shared__ float  s_red[4];
    __shared__ int    s_cnt;

    const int bid = blockIdx.x;          // 0..2047
    const int t   = threadIdx.x;
    const int b   = bid >> 8;            // 256 tiles per batch
    const int ty  = (bid >> 4) & 15;
    const int tx  = bid & 15;
    const float y0f = (float)(ty * TS);
    const float x0f = (float)(tx * TS);

    if (t == 0) s_cnt = 0;

    // ---- Pruning prologue (threads 0..99 hold one point each) ----
    float dmax2 = INF;
    float dmin2 = 0.0f, c0 = 0.0f, c1 = 0.0f, c2 = 0.0f;
    if (t < 2 * N) {
        const int* src = (t < N) ? pos : neg;
        const int  idx = (t < N) ? t : t - N;
        int2 p = ((const int2*)src)[b * N + idx];
        const float fy = (float)p.x, fx = (float)p.y;   // (ycoord, xcoord)
        const float tag = (t < N) ? 1.0f : 0.0f;
        const float yhi = y0f + (float)(TS - 1), xhi = x0f + (float)(TS - 1);
        float dy = fmaxf(fmaxf(y0f - fy, fy - yhi), 0.0f);
        float dx = fmaxf(fmaxf(x0f - fx, fx - xhi), 0.0f);
        dmin2 = dy * dy + dx * dx;                       // exact ints
        float dyM = fmaxf(fy - y0f, yhi - fy);
        float dxM = fmaxf(fx - x0f, xhi - fx);
        dmax2 = dyM * dyM + dxM * dxM;
        c0 = -4.0f * fx;
        c1 = -4.0f * fy;
        c2 = 2.0f * (fx * fx + fy * fy) + tag;           // < 2^21, exact
    }
    // block-min of dmax2 -> pruning bound
    float m = dmax2;
    #pragma unroll
    for (int off = 32; off > 0; off >>= 1)
        m = fminf(m, __shfl_down(m, off, 64));
    if ((t & 63) == 0) s_red[t >> 6] = m;
    __syncthreads();
    const float bound = fminf(fminf(s_red[0], s_red[1]),
                              fminf(s_red[2], s_red[3]));
    if (t < 2 * N && dmin2 <= bound) {
        int k = atomicAdd(&s_cnt, 1);    // LDS atomic, order-free (min comm.)
        s_pts[k] = make_float4(c0, c1, c2, 0.0f);
    }
    __syncthreads();
    if (t == 0) {                        // pad to multiple of 4 with sentinels
        int k0 = s_cnt, kp = (k0 + 3) & ~3;
        for (int i = k0; i < kp; ++i)
            s_pts[i] = make_float4(0.0f, 0.0f, INF, 0.0f);
        s_cnt = kp;
    }
    __syncthreads();
    const int K = s_cnt;

    // ---- Pixel loop: 4 consecutive px per thread ----
    const int r   = t >> 3;              // row in tile 0..31
    const int cc  = (t & 7) << 2;        // col base 0..28
    const int y   = ty * TS + r;
    const int x   = tx * TS + cc;
    const float yf = (float)y;
    const float xf = (float)x;

    float mn[4] = {INF, INF, INF, INF};
    for (int n = 0; n < K; n += 4) {
        #pragma unroll
        for (int j = 0; j < 4; ++j) {
            float4 P = s_pts[n + j];
            float cy = fmaf(P.y, yf, P.z);
            mn[0] = fminf(mn[0], fmaf(P.x, xf,          cy));
            mn[1] = fminf(mn[1], fmaf(P.x, xf + 1.0f,   cy));
            mn[2] = fminf(mn[2], fmaf(P.x, xf + 2.0f,   cy));
            mn[3] = fminf(mn[3], fmaf(P.x, xf + 3.0f,   cy));
        }
    }

    const size_t pix = ((size_t)(b * H + y)) * W + x;
    float4 xv = *(const float4*)(out + pix);        // 16B-aligned
    const float xs[4] = {xv.x, xv.y, xv.z, xv.w};

    float lsum = 0.0f;
    #pragma unroll
    for (int j = 0; j < 4; ++j) {
        int mi = (int)mn[j];                        // exact signed int
        float z = (float)(mi & 1);                  // parity -> mask
        dout[1 + pix + j] = z;
        float xx = xs[j];
        lsum += fmaxf(xx, 0.0f) - xx * z + __logf(1.0f + __expf(-fabsf(xx)));
    }

    // ---- deterministic block reduction of loss ----
    #pragma unroll
    for (int off = 32; off > 0; off >>= 1)
        lsum += __shfl_down(lsum, off, 64);
    __syncthreads();                     // s_red reuse safe
    if ((t & 63) == 0) s_red[t >> 6] = lsum;
    __syncthreads();
    if (t == 0)
        partials[bid] = (s_red[0] + s_red[1]) + (s_red[2] + s_red[3]);
}

// Kernel 2: deterministic final reduction of 2048 block partials -> mean.
// Stream ordering makes kernel-1 stores visible; no atomics needed.
__global__ __launch_bounds__(256) void psl_finish(
    const float* __restrict__ partials,
    float*       __restrict__ dout)
{
    __shared__ float s_red[4];
    const int t = threadIdx.x;
    float s = ((partials[t]        + partials[t + 256]) +
               (partials[t + 512]  + partials[t + 768])) +
              ((partials[t + 1024] + partials[t + 1280]) +
               (partials[t + 1536] + partials[t + 1792]));
    #pragma unroll
    for (int off = 32; off > 0; off >>= 1)
        s += __shfl_down(s, off, 64);
    if ((t & 63) == 0) s_red[t >> 6] = s;
    __syncthreads();
    if (t == 0)
        dout[0] = ((s_red[0] + s_red[1]) + (s_red[2] + s_red[3])) *
                  (1.0f / (float)(B * H * W));
}

extern "C" void kernel_launch(void* const* d_in, const int* in_sizes, int n_in,
                              void* d_out, int out_size, void* d_ws, size_t ws_size,
                              hipStream_t stream) {
    const float* out_logits = (const float*)d_in[0];
    const int*   pos        = (const int*)d_in[1];
    const int*   neg        = (const int*)d_in[2];
    float* dout     = (float*)d_out;
    float* partials = (float*)d_ws;      // 2048 floats

    psl_main<<<NBLOCKS, 256, 0, stream>>>(out_logits, pos, neg, dout, partials);
    psl_finish<<<1, 256, 0, stream>>>(partials, dout);
}